// Round 7
// baseline (179.980 us; speedup 1.0000x reference)
//
#include <hip/hip_runtime.h>
#include <math.h>

#define NEG_SLOPE 0.2f
#define BSHIFT 8            // 256 nodes per bucket
#define MAXBUK 512          // supports N up to 131072

typedef __attribute__((ext_vector_type(8))) short short8;   // 8 bf16 (MFMA A/B frag)
typedef __attribute__((ext_vector_type(4))) float floatx4;  // MFMA C/D frag

static __device__ __forceinline__ float lrelu_exp(float e) {
    e = fmaxf(e, NEG_SLOPE * e);
    return __expf(e);
}

// fp32 -> bf16 (round-to-nearest-even)
static __device__ __forceinline__ short f2bf(float f) {
    union { float f; unsigned u; } v; v.f = f;
    unsigned r = v.u + 0x7FFFu + ((v.u >> 16) & 1u);
    return (short)(r >> 16);
}
// bf16 bits -> fp32 (exact)
static __device__ __forceinline__ float bf2f(unsigned short s) {
    union { float f; unsigned u; } v;
    v.u = ((unsigned)s) << 16;
    return v.f;
}
// packed pair of bf16 -> two fp32 (1 shift / 1 and)
static __device__ __forceinline__ float bfpair_lo(unsigned v) {
    union { float f; unsigned u; } x; x.u = v << 16; return x.f;
}
static __device__ __forceinline__ float bfpair_hi(unsigned v) {
    union { float f; unsigned u; } x; x.u = v & 0xffff0000u; return x.f;
}
// split f into hi+lo bf16 pair (covers ~16 mantissa bits)
static __device__ __forceinline__ void splitbf(float f, short& hi, short& lo) {
    hi = f2bf(f);
    lo = f2bf(f - bf2f((unsigned short)hi));
}

// ================= CSR build: LDS-bucketed partition (no global data atomics) =================

__global__ __launch_bounds__(512) void k_hist(const int* __restrict__ dst, int E, int CHUNK,
                                              int NBLK, int NBUK, int* __restrict__ blockhist) {
    __shared__ int hist[MAXBUK];
    int t = threadIdx.x, b = blockIdx.x;
    for (int i = t; i < NBUK; i += 512) hist[i] = 0;
    __syncthreads();
    int e0 = b * CHUNK, e1 = e0 + CHUNK; if (e1 > E) e1 = E;
    for (int e = e0 + t; e < e1; e += 512) atomicAdd(&hist[dst[e] >> BSHIFT], 1);
    __syncthreads();
    for (int i = t; i < NBUK; i += 512) blockhist[(size_t)i * NBLK + b] = hist[i];
}

// Per-bucket LOCAL exclusive scan across NBLK block-counts (carry loop), writes bucket total.
__global__ __launch_bounds__(256) void k_colscan(int* __restrict__ blockhist,
                                                 int* __restrict__ btot, int NBLK) {
    int bucket = blockIdx.x, t = threadIdx.x;
    int lane = t & 63, wv = t >> 6;
    __shared__ int wsum[4];
    __shared__ int carry_s;
    if (t == 0) carry_s = 0;
    __syncthreads();
    for (int base = 0; base < NBLK; base += 256) {
        int idx = base + t;
        int v = (idx < NBLK) ? blockhist[(size_t)bucket * NBLK + idx] : 0;
        int s = v;
#pragma unroll
        for (int o = 1; o < 64; o <<= 1) {
            int u = __shfl_up(s, o, 64);
            if (lane >= o) s += u;
        }
        if (lane == 63) wsum[wv] = s;
        __syncthreads();
        int b0 = 0;
#pragma unroll
        for (int w = 0; w < 4; ++w) b0 += (w < wv) ? wsum[w] : 0;
        int excl = s + b0 - v + carry_s;
        if (idx < NBLK) blockhist[(size_t)bucket * NBLK + idx] = excl;
        __syncthreads();
        if (t == 255) carry_s += s + b0;   // chunk total
        __syncthreads();
    }
    if (t == 0) btot[bucket] = carry_s;
}

// Exclusive scan over NBUK bucket totals (NBUK <= 512).
__global__ __launch_bounds__(512) void k_bucket_scan(const int* __restrict__ btot,
                                                     int* __restrict__ bucketbase, int NBUK) {
    __shared__ int sh[512];
    int t = threadIdx.x;
    int v = (t < NBUK) ? btot[t] : 0;
    sh[t] = v;
    __syncthreads();
#pragma unroll
    for (int o = 1; o < 512; o <<= 1) {
        int u = (t >= o) ? sh[t - o] : 0;
        __syncthreads();
        sh[t] += u;
        __syncthreads();
    }
    if (t < NBUK) bucketbase[t] = sh[t] - v;
    if (t == NBUK - 1) bucketbase[NBUK] = sh[t];
}

// packed record: (src << 8) | (dst & 255)   [src < 2^24; bucket id recovers dst high bits]
__global__ __launch_bounds__(512) void k_partition(const int* __restrict__ src,
                                                   const int* __restrict__ dst, int E, int CHUNK,
                                                   int NBLK, int NBUK,
                                                   const int* __restrict__ blockhist,
                                                   const int* __restrict__ bucketbase,
                                                   unsigned* __restrict__ packed) {
    __shared__ int cur[MAXBUK];
    int t = threadIdx.x, b = blockIdx.x;
    for (int i = t; i < NBUK; i += 512)
        cur[i] = blockhist[(size_t)i * NBLK + b] + bucketbase[i];
    __syncthreads();
    int e0 = b * CHUNK, e1 = e0 + CHUNK; if (e1 > E) e1 = E;
    for (int e = e0 + t; e < e1; e += 512) {
        int d = dst[e], s = src[e];
        int pos = atomicAdd(&cur[d >> BSHIFT], 1);
        packed[pos] = ((unsigned)s << 8) | ((unsigned)d & 255u);
    }
}

__global__ __launch_bounds__(256) void k_fine(const unsigned* __restrict__ packed,
                                              const int* __restrict__ bucketbase,
                                              int* __restrict__ offsets,
                                              int* __restrict__ csr_src,
                                              int N, int NBUK) {
    __shared__ int fcnt[256];
    __shared__ int wsum[4];
    int bucket = blockIdx.x, t = threadIdx.x;
    int lo = bucket << BSHIFT;
    int nn = N - lo; if (nn > 256) nn = 256;
    int ebase = bucketbase[bucket];
    int ecnt = bucketbase[bucket + 1] - ebase;
    fcnt[t] = 0;
    __syncthreads();
    for (int i = t; i < ecnt; i += 256) {
        unsigned p = packed[ebase + i];
        atomicAdd(&fcnt[p & 255u], 1);
    }
    __syncthreads();
    int v = fcnt[t];
    int lane = t & 63, wv = t >> 6;
    int s = v;
#pragma unroll
    for (int o = 1; o < 64; o <<= 1) {
        int u = __shfl_up(s, o, 64);
        if (lane >= o) s += u;
    }
    if (lane == 63) wsum[wv] = s;
    __syncthreads();
    int base = 0;
#pragma unroll
    for (int w = 0; w < 4; ++w) base += (w < wv) ? wsum[w] : 0;
    int excl = s + base - v;
    if (t < nn) offsets[lo + t] = ebase + excl;
    if (bucket == NBUK - 1 && t == 0) offsets[N] = ebase + ecnt;  // == E
    __syncthreads();
    fcnt[t] = excl;   // reuse as cursor
    __syncthreads();
    for (int i = t; i < ecnt; i += 256) {
        unsigned p = packed[ebase + i];
        int pos = atomicAdd(&fcnt[p & 255u], 1);
        csr_src[ebase + pos] = (int)(p >> 8);
    }
}

// ---------------- Weight prep: W1 -> bf16 transposed [64 n][128 k] (contiguous in k) ---------
__global__ __launch_bounds__(256) void k_prepW1(const float* __restrict__ W1,
                                                short* __restrict__ w1t) {
    int i = blockIdx.x * 256 + threadIdx.x;   // 64*128 = 8192
    if (i < 64 * 128) {
        int n = i >> 7, k = i & 127;
        w1t[i] = f2bf(W1[k * 64 + n]);
    }
}

// ---------------- W2 pre-split TRANSPOSED: hi/lo bf16, [48 n][64 k] (contiguous in k) --------
__global__ __launch_bounds__(256) void k_splitW2(const float* __restrict__ W2,
                                                 short* __restrict__ w2ht,
                                                 short* __restrict__ w2lt) {
    int i = blockIdx.x * 256 + threadIdx.x;   // 48*64 = 3072
    if (i < 48 * 64) {
        int n = i >> 6, k = i & 63;
        short hi = 0, lo = 0;
        if (n < 40) splitbf(W2[k * 40 + n], hi, lo);
        w2ht[i] = hi; w2lt[i] = lo;
    }
}

// ---------------- Layer 1 GEMM via MFMA bf16 (R18: vector B-frag loads from w1t) ------------
__global__ __launch_bounds__(256) void k_gemm1(const float* __restrict__ x,
                                               const short* __restrict__ w1t,
                                               const float* __restrict__ att_s,
                                               const float* __restrict__ att_d,
                                               unsigned short* __restrict__ h1b,
                                               float* __restrict__ a_s1,
                                               float* __restrict__ a_d1, int N) {
    int tid = threadIdx.x, wave = tid >> 6, lane = tid & 63;
    int n16 = lane & 15, q = lane >> 4;
    int nb = blockIdx.x * 64 + wave * 16;
    if (nb >= N) return;

    short8 bfr[4][4];
#pragma unroll
    for (int ct = 0; ct < 4; ++ct) {
        int n = ct * 16 + n16;
#pragma unroll
        for (int kc = 0; kc < 4; ++kc)
            bfr[ct][kc] = *(const short8*)(w1t + n * 128 + kc * 32 + q * 8);
    }

    int arow = nb + n16; if (arow >= N) arow = N - 1;
    const float* xr = x + (size_t)arow * 128 + q * 8;
    short8 afr[4];
#pragma unroll
    for (int kc = 0; kc < 4; ++kc) {
        float4 u0 = *(const float4*)(xr + kc * 32);
        float4 u1 = *(const float4*)(xr + kc * 32 + 4);
        short8 a;
        a[0] = f2bf(u0.x); a[1] = f2bf(u0.y); a[2] = f2bf(u0.z); a[3] = f2bf(u0.w);
        a[4] = f2bf(u1.x); a[5] = f2bf(u1.y); a[6] = f2bf(u1.z); a[7] = f2bf(u1.w);
        afr[kc] = a;
    }

    floatx4 acc[4];
#pragma unroll
    for (int ct = 0; ct < 4; ++ct) {
        floatx4 c = {0.f, 0.f, 0.f, 0.f};
#pragma unroll
        for (int kc = 0; kc < 4; ++kc)
            c = __builtin_amdgcn_mfma_f32_16x16x32_bf16(afr[kc], bfr[ct][kc], c, 0, 0, 0);
        acc[ct] = c;
    }

#pragma unroll
    for (int ct = 0; ct < 4; ++ct) {
#pragma unroll
        for (int r = 0; r < 4; ++r) {
            int row = nb + q * 4 + r;
            if (row < N) h1b[(size_t)row * 64 + ct * 16 + n16] = (unsigned short)f2bf(acc[ct][r]);
        }
    }

#pragma unroll
    for (int ct = 0; ct < 4; ++ct) {
        float as = att_s[ct * 16 + n16];
        float ad = att_d[ct * 16 + n16];
#pragma unroll
        for (int r = 0; r < 4; ++r) {
            float ps = acc[ct][r] * as;
            float pd = acc[ct][r] * ad;
#pragma unroll
            for (int m = 1; m < 8; m <<= 1) {
                ps += __shfl_xor(ps, m, 64);
                pd += __shfl_xor(pd, m, 64);
            }
            int row = nb + q * 4 + r;
            if ((n16 & 7) == 0 && row < N) {
                int h = 2 * ct + (n16 >> 3);
                a_s1[row * 8 + h] = ps;
                a_d1[row * 8 + h] = pd;
            }
        }
    }
}

// ---------------- Layer 1 aggregation: R16 node-per-quarter + 4-deep gather batching --------
// (proven best: 49.8 us; L2-miss-traffic bound at ~155 MB/dispatch -> structural floor)
__global__ __launch_bounds__(256) void k_agg1(const unsigned short* __restrict__ h1b,
                                              const float* __restrict__ a_s1,
                                              const float* __restrict__ a_d1,
                                              const int* __restrict__ offsets,
                                              const int* __restrict__ csr_src,
                                              const float* __restrict__ b1,
                                              float* __restrict__ y1, int N) {
    int wave = threadIdx.x >> 6, lane = threadIdx.x & 63;
    int q = lane >> 4;                   // quarter = node slot
    int ll = lane & 15;                  // lane within quarter
    int d = (blockIdx.x * 4 + wave) * 4 + q;
    bool dvalid = (d < N);
    int de = dvalid ? d : N - 1;
    int g = ll >> 3;                     // edge slot 0..1
    int c = ll & 7;                      // chunk == head
    float ad = a_d1[de * 8 + c];
    int i0 = offsets[de];
    int deg = dvalid ? (offsets[de + 1] - i0) : 0;
    int dmax = deg;
    dmax = max(dmax, __shfl_xor(dmax, 16, 64));
    dmax = max(dmax, __shfl_xor(dmax, 32, 64));
    float acc[8] = {0.f, 0.f, 0.f, 0.f, 0.f, 0.f, 0.f, 0.f};
    float wsum_l = 0.f;
    if (g == 0) {                        // self-loop on slot 0
        float w0 = lrelu_exp(a_s1[de * 8 + c] + ad);
        uint4 v = *(const uint4*)(h1b + (size_t)de * 64 + 8 * c);
        acc[0] = w0 * bfpair_lo(v.x); acc[1] = w0 * bfpair_hi(v.x);
        acc[2] = w0 * bfpair_lo(v.y); acc[3] = w0 * bfpair_hi(v.y);
        acc[4] = w0 * bfpair_lo(v.z); acc[5] = w0 * bfpair_hi(v.z);
        acc[6] = w0 * bfpair_lo(v.w); acc[7] = w0 * bfpair_hi(v.w);
        wsum_l = w0;
    }
    for (int j = 0; j < dmax; j += 8) {
        int b0 = i0 + j + 4 * g;
        int idx[4]; bool lv[4];
#pragma unroll
        for (int u = 0; u < 4; ++u) {
            int jj = j + 4 * g + u;
            lv[u] = (jj < deg);
            idx[u] = de;
            if (lv[u]) idx[u] = csr_src[b0 + u];
        }
        float ev[4];
#pragma unroll
        for (int u = 0; u < 4; ++u) ev[u] = a_s1[idx[u] * 8 + c] + ad;
        uint4 vv[4];
#pragma unroll
        for (int u = 0; u < 4; ++u)
            vv[u] = *(const uint4*)(h1b + (size_t)idx[u] * 64 + 8 * c);
#pragma unroll
        for (int u = 0; u < 4; ++u) {
            float w = lv[u] ? lrelu_exp(ev[u]) : 0.f;
            wsum_l += w;
            acc[0] = fmaf(w, bfpair_lo(vv[u].x), acc[0]);
            acc[1] = fmaf(w, bfpair_hi(vv[u].x), acc[1]);
            acc[2] = fmaf(w, bfpair_lo(vv[u].y), acc[2]);
            acc[3] = fmaf(w, bfpair_hi(vv[u].y), acc[3]);
            acc[4] = fmaf(w, bfpair_lo(vv[u].z), acc[4]);
            acc[5] = fmaf(w, bfpair_hi(vv[u].z), acc[5]);
            acc[6] = fmaf(w, bfpair_lo(vv[u].w), acc[6]);
            acc[7] = fmaf(w, bfpair_hi(vv[u].w), acc[7]);
        }
    }
    // fold slot 1 into slot 0 (same c): +8 within quarter; wsum rides along (head==chunk)
#pragma unroll
    for (int k = 0; k < 8; ++k) acc[k] += __shfl(acc[k], lane + 8, 64);
    wsum_l += __shfl(wsum_l, lane + 8, 64);
    if (g == 0 && dvalid) {
        float inv = 1.f / (wsum_l + 1e-16f);
        float4 bA = *(const float4*)(b1 + 8 * c);
        float4 bB = *(const float4*)(b1 + 8 * c + 4);
        float o[8];
        o[0] = acc[0] * inv + bA.x;
        o[1] = acc[1] * inv + bA.y;
        o[2] = acc[2] * inv + bA.z;
        o[3] = acc[3] * inv + bA.w;
        o[4] = acc[4] * inv + bB.x;
        o[5] = acc[5] * inv + bB.y;
        o[6] = acc[6] * inv + bB.z;
        o[7] = acc[7] * inv + bB.w;
#pragma unroll
        for (int k = 0; k < 8; ++k) o[k] = o[k] > 0.f ? o[k] : (__expf(o[k]) - 1.f);
        float4 s0 = make_float4(o[0], o[1], o[2], o[3]);
        float4 s1 = make_float4(o[4], o[5], o[6], o[7]);
        *(float4*)(y1 + (size_t)d * 64 + 8 * c) = s0;       // fp32 (precision-critical)
        *(float4*)(y1 + (size_t)d * 64 + 8 * c + 4) = s1;
    }
}

// ---------------- Layer 2 GEMM, split-bf16 (R18: vector B-frag loads from w2ht/w2lt) --------
__global__ __launch_bounds__(256) void k_gemm2(const float* __restrict__ y1,
                                               const short* __restrict__ w2ht,
                                               const short* __restrict__ w2lt,
                                               const float* __restrict__ att_s,
                                               const float* __restrict__ att_d,
                                               unsigned short* __restrict__ h2b,
                                               float* __restrict__ a2s,
                                               float* __restrict__ a2d, int N) {
    int tid = threadIdx.x, wave = tid >> 6, lane = tid & 63;
    int n16 = lane & 15, q = lane >> 4;
    int nb = blockIdx.x * 64 + wave * 16;
    if (nb >= N) return;

    int arow = nb + n16; if (arow >= N) arow = N - 1;
    const float* yr = y1 + (size_t)arow * 64 + q * 8;
    short8 ah[2], al[2];
#pragma unroll
    for (int kc = 0; kc < 2; ++kc) {
        float4 u0 = *(const float4*)(yr + kc * 32);
        float4 u1 = *(const float4*)(yr + kc * 32 + 4);
        short8 h, l; short hi, lo;
        splitbf(u0.x, hi, lo); h[0] = hi; l[0] = lo;
        splitbf(u0.y, hi, lo); h[1] = hi; l[1] = lo;
        splitbf(u0.z, hi, lo); h[2] = hi; l[2] = lo;
        splitbf(u0.w, hi, lo); h[3] = hi; l[3] = lo;
        splitbf(u1.x, hi, lo); h[4] = hi; l[4] = lo;
        splitbf(u1.y, hi, lo); h[5] = hi; l[5] = lo;
        splitbf(u1.z, hi, lo); h[6] = hi; l[6] = lo;
        splitbf(u1.w, hi, lo); h[7] = hi; l[7] = lo;
        ah[kc] = h; al[kc] = l;
    }

    float psr[4] = {0.f, 0.f, 0.f, 0.f}, pdr[4] = {0.f, 0.f, 0.f, 0.f};
#pragma unroll
    for (int ct = 0; ct < 3; ++ct) {
        int n = ct * 16 + n16;
        short8 bh0 = *(const short8*)(w2ht + n * 64 + q * 8);
        short8 bh1 = *(const short8*)(w2ht + n * 64 + 32 + q * 8);
        short8 bl0 = *(const short8*)(w2lt + n * 64 + q * 8);
        short8 bl1 = *(const short8*)(w2lt + n * 64 + 32 + q * 8);
        floatx4 c = {0.f, 0.f, 0.f, 0.f};
        c = __builtin_amdgcn_mfma_f32_16x16x32_bf16(ah[0], bl0, c, 0, 0, 0);
        c = __builtin_amdgcn_mfma_f32_16x16x32_bf16(al[0], bh0, c, 0, 0, 0);
        c = __builtin_amdgcn_mfma_f32_16x16x32_bf16(ah[0], bh0, c, 0, 0, 0);
        c = __builtin_amdgcn_mfma_f32_16x16x32_bf16(ah[1], bl1, c, 0, 0, 0);
        c = __builtin_amdgcn_mfma_f32_16x16x32_bf16(al[1], bh1, c, 0, 0, 0);
        c = __builtin_amdgcn_mfma_f32_16x16x32_bf16(ah[1], bh1, c, 0, 0, 0);

        int col = ct * 16 + n16;
#pragma unroll
        for (int r = 0; r < 4; ++r) {
            int row = nb + q * 4 + r;
            if (col < 40 && row < N) h2b[(size_t)row * 40 + col] = (unsigned short)f2bf(c[r]);
        }
        float asv = (col < 40) ? att_s[col] : 0.f;
        float adv = (col < 40) ? att_d[col] : 0.f;
#pragma unroll
        for (int r = 0; r < 4; ++r) {
            psr[r] = fmaf(c[r], asv, psr[r]);
            pdr[r] = fmaf(c[r], adv, pdr[r]);
        }
    }
#pragma unroll
    for (int r = 0; r < 4; ++r) {
        float ps = psr[r], pd = pdr[r];
#pragma unroll
        for (int m = 1; m < 16; m <<= 1) {
            ps += __shfl_xor(ps, m, 64);
            pd += __shfl_xor(pd, m, 64);
        }
        int row = nb + q * 4 + r;
        if (n16 == 0 && row < N) { a2s[row] = ps; a2d[row] = pd; }
    }
}

// ---------------- Layer 2 aggregation: R16 node-per-quarter + 4-deep gather batching --------
__global__ __launch_bounds__(256) void k_agg2(const unsigned short* __restrict__ h2b,
                                              const float* __restrict__ a2s,
                                              const float* __restrict__ a2d,
                                              const int* __restrict__ offsets,
                                              const int* __restrict__ csr_src,
                                              const float* __restrict__ b2,
                                              float* __restrict__ out, int N) {
    int wave = threadIdx.x >> 6, lane = threadIdx.x & 63;
    int q = lane >> 4;                   // quarter = node slot
    int ll = lane & 15;                  // lane within quarter
    int d = (blockIdx.x * 4 + wave) * 4 + q;
    bool dvalid = (d < N);
    int de = dvalid ? d : N - 1;
    int g = ll / 5;                      // edge slot 0..2 (3 for idle lane 15)
    int c = ll - g * 5;                  // 16B chunk 0..4
    bool lane_ok = (ll < 15);
    float ad = a2d[de];
    float w0 = lrelu_exp(a2s[de] + ad);
    int i0 = offsets[de];
    int deg = offsets[de + 1] - i0;
    if (!dvalid) deg = 0;
    int dmax = deg;
    dmax = max(dmax, __shfl_xor(dmax, 16, 64));
    dmax = max(dmax, __shfl_xor(dmax, 32, 64));
    float acc[8] = {0.f, 0.f, 0.f, 0.f, 0.f, 0.f, 0.f, 0.f};
    float wsum_l = 0.f;
    if (g == 0) {                        // self-loop handled by g==0 lanes (ll 0..4)
        uint4 v = *(const uint4*)(h2b + (size_t)de * 40 + 8 * c);
        acc[0] = w0 * bfpair_lo(v.x); acc[1] = w0 * bfpair_hi(v.x);
        acc[2] = w0 * bfpair_lo(v.y); acc[3] = w0 * bfpair_hi(v.y);
        acc[4] = w0 * bfpair_lo(v.z); acc[5] = w0 * bfpair_hi(v.z);
        acc[6] = w0 * bfpair_lo(v.w); acc[7] = w0 * bfpair_hi(v.w);
    }
    for (int j = 0; j < dmax; j += 12) {
        int b0 = i0 + j + 4 * g;
        int idx[4]; bool lv[4];
#pragma unroll
        for (int u = 0; u < 4; ++u) {
            int jj = j + 4 * g + u;
            lv[u] = lane_ok && (jj < deg);
            idx[u] = de;
            if (lv[u]) idx[u] = csr_src[b0 + u];
        }
        float ev[4];
#pragma unroll
        for (int u = 0; u < 4; ++u) ev[u] = a2s[idx[u]] + ad;
        uint4 vv[4];
#pragma unroll
        for (int u = 0; u < 4; ++u)
            vv[u] = *(const uint4*)(h2b + (size_t)idx[u] * 40 + 8 * c);
#pragma unroll
        for (int u = 0; u < 4; ++u) {
            float w = lv[u] ? lrelu_exp(ev[u]) : 0.f;
            if (c == 0) wsum_l += w;     // one counting lane per (quarter, slot)
            acc[0] = fmaf(w, bfpair_lo(vv[u].x), acc[0]);
            acc[1] = fmaf(w, bfpair_hi(vv[u].x), acc[1]);
            acc[2] = fmaf(w, bfpair_lo(vv[u].y), acc[2]);
            acc[3] = fmaf(w, bfpair_hi(vv[u].y), acc[3]);
            acc[4] = fmaf(w, bfpair_lo(vv[u].z), acc[4]);
            acc[5] = fmaf(w, bfpair_hi(vv[u].z), acc[5]);
            acc[6] = fmaf(w, bfpair_lo(vv[u].w), acc[6]);
            acc[7] = fmaf(w, bfpair_hi(vv[u].w), acc[7]);
        }
    }
    // fold 3 edge slots into g==0 lanes (same c): +5, +10 within quarter
#pragma unroll
    for (int k = 0; k < 8; ++k)
        acc[k] += __shfl(acc[k], lane + 5, 64) + __shfl(acc[k], lane + 10, 64);
    wsum_l += __shfl(wsum_l, lane + 5, 64) + __shfl(wsum_l, lane + 10, 64);
    wsum_l = __shfl(wsum_l, lane & 48, 64);       // broadcast quarter total (from ll==0)
    float wsum = wsum_l + w0;
    bool act5 = (ll < 5) && dvalid;
    float inv = 1.f / (wsum + 1e-16f);
    float4 bA = *(const float4*)(b2 + 8 * c);
    float4 bB = *(const float4*)(b2 + 8 * c + 4);
    float o[8];
    o[0] = acc[0] * inv + bA.x;
    o[1] = acc[1] * inv + bA.y;
    o[2] = acc[2] * inv + bA.z;
    o[3] = acc[3] * inv + bA.w;
    o[4] = acc[4] * inv + bB.x;
    o[5] = acc[5] * inv + bB.y;
    o[6] = acc[6] * inv + bB.z;
    o[7] = acc[7] * inv + bB.w;
    // log_softmax over 40 ch: ll 0..4 hold 8 each; 3-step butterfly inside 8-lane group
    float mxl = -INFINITY;
    if (act5) {
        mxl = fmaxf(fmaxf(fmaxf(o[0], o[1]), fmaxf(o[2], o[3])),
                    fmaxf(fmaxf(o[4], o[5]), fmaxf(o[6], o[7])));
    }
#pragma unroll
    for (int mm = 1; mm < 8; mm <<= 1) mxl = fmaxf(mxl, __shfl_xor(mxl, mm, 64));
    float exl = 0.f;
    if (act5) {
#pragma unroll
        for (int k = 0; k < 8; ++k) exl += __expf(o[k] - mxl);
    }
#pragma unroll
    for (int mm = 1; mm < 8; mm <<= 1) exl += __shfl_xor(exl, mm, 64);
    if (act5) {
        float lse = mxl + __logf(exl);
        float4 s0 = make_float4(o[0] - lse, o[1] - lse, o[2] - lse, o[3] - lse);
        float4 s1 = make_float4(o[4] - lse, o[5] - lse, o[6] - lse, o[7] - lse);
        *(float4*)(out + (size_t)d * 40 + 8 * c) = s0;
        *(float4*)(out + (size_t)d * 40 + 8 * c + 4) = s1;
    }
}

// ---------------- launcher ----------------

extern "C" void kernel_launch(void* const* d_in, const int* in_sizes, int n_in,
                              void* d_out, int out_size, void* d_ws, size_t ws_size,
                              hipStream_t stream) {
    const float* x   = (const float*)d_in[0];
    const int*   ei  = (const int*)d_in[1];
    const float* W1  = (const float*)d_in[2];
    const float* as1 = (const float*)d_in[3];
    const float* ad1 = (const float*)d_in[4];
    const float* b1  = (const float*)d_in[5];
    const float* W2  = (const float*)d_in[6];
    const float* as2 = (const float*)d_in[7];
    const float* ad2 = (const float*)d_in[8];
    const float* b2  = (const float*)d_in[9];
    float* out = (float*)d_out;

    int N = in_sizes[0] / 128;   // 100000
    int E = in_sizes[1] / 2;     // 1600000
    const int* src = ei;
    const int* dst = ei + E;

    int NBUK = (N + 255) >> BSHIFT;          // 391
    int CHUNK = 4096;
    int NBLK = (E + CHUNK - 1) / CHUNK;      // 391

    char* ws = (char*)d_ws;
    size_t off = 0;
    auto alloc = [&](size_t bytes) -> char* {
        char* p = ws + off;
        off += (bytes + 255) & ~(size_t)255;
        return p;
    };
    unsigned short* h1b = (unsigned short*)alloc((size_t)N * 64 * 2);   // bf16
    float* a_s1    = (float*)alloc((size_t)N * 8 * 4);
    float* a_d1    = (float*)alloc((size_t)N * 8 * 4);
    float* y1      = (float*)alloc((size_t)N * 64 * 4);                 // fp32 (precision-critical)
    // h2b (bf16, 8 MB) and packed (uint, 6.4 MB) are temporally disjoint: share region.
    size_t shared_sz = (size_t)N * 40 * 2;
    if ((size_t)E * 4 > shared_sz) shared_sz = (size_t)E * 4;
    char*  region  = alloc(shared_sz);
    unsigned short* h2b = (unsigned short*)region;
    unsigned* packed    = (unsigned*)region;
    float* a2s     = (float*)alloc((size_t)N * 4);
    float* a2d     = (float*)alloc((size_t)N * 4);
    int*   offsets = (int*)alloc((size_t)(N + 1) * 4);
    int*   csr_src = (int*)alloc((size_t)E * 4);
    int*   blockhist  = (int*)alloc((size_t)NBUK * NBLK * 4);
    int*   btot       = (int*)alloc((size_t)NBUK * 4);
    int*   bucketbase = (int*)alloc((size_t)(NBUK + 1) * 4);
    short* w1t     = (short*)alloc((size_t)64 * 128 * 2);
    short* w2ht    = (short*)alloc((size_t)48 * 64 * 2);
    short* w2lt    = (short*)alloc((size_t)48 * 64 * 2);

    int nb1 = (N + 15) / 16;     // agg1: 16 nodes per block (4 waves x 4 quarters)
    int nb2 = (N + 15) / 16;     // agg2: 16 nodes per block (4 waves x 4 quarters)
    int gb = (N + 63) / 64;

    k_hist<<<NBLK, 512, 0, stream>>>(dst, E, CHUNK, NBLK, NBUK, blockhist);
    k_colscan<<<NBUK, 256, 0, stream>>>(blockhist, btot, NBLK);
    k_bucket_scan<<<1, 512, 0, stream>>>(btot, bucketbase, NBUK);
    k_partition<<<NBLK, 512, 0, stream>>>(src, dst, E, CHUNK, NBLK, NBUK, blockhist,
                                          bucketbase, packed);
    k_fine<<<NBUK, 256, 0, stream>>>(packed, bucketbase, offsets, csr_src, N, NBUK);
    k_prepW1<<<32, 256, 0, stream>>>(W1, w1t);
    k_splitW2<<<12, 256, 0, stream>>>(W2, w2ht, w2lt);
    k_gemm1<<<gb, 256, 0, stream>>>(x, w1t, as1, ad1, h1b, a_s1, a_d1, N);
    k_agg1<<<nb1, 256, 0, stream>>>(h1b, a_s1, a_d1, offsets, csr_src, b1, y1, N);
    k_gemm2<<<gb, 256, 0, stream>>>(y1, w2ht, w2lt, as2, ad2, h2b, a2s, a2d, N);
    k_agg2<<<nb2, 256, 0, stream>>>(h2b, a2s, a2d, offsets, csr_src, b2, out, N);
}

// Round 8
// 171.379 us; speedup vs baseline: 1.0502x; 1.0502x over previous
//
#include <hip/hip_runtime.h>
#include <math.h>

#define NEG_SLOPE 0.2f
#define BSHIFT 8            // 256 nodes per bucket
#define MAXBUK 512          // supports N up to 131072

typedef __attribute__((ext_vector_type(8))) short short8;   // 8 bf16 (MFMA A/B frag)
typedef __attribute__((ext_vector_type(4))) float floatx4;  // MFMA C/D frag

static __device__ __forceinline__ float lrelu_exp(float e) {
    e = fmaxf(e, NEG_SLOPE * e);
    return __expf(e);
}

// fp32 -> bf16 (round-to-nearest-even)
static __device__ __forceinline__ short f2bf(float f) {
    union { float f; unsigned u; } v; v.f = f;
    unsigned r = v.u + 0x7FFFu + ((v.u >> 16) & 1u);
    return (short)(r >> 16);
}
// bf16 bits -> fp32 (exact)
static __device__ __forceinline__ float bf2f(unsigned short s) {
    union { float f; unsigned u; } v;
    v.u = ((unsigned)s) << 16;
    return v.f;
}
// packed pair of bf16 -> two fp32 (1 shift / 1 and)
static __device__ __forceinline__ float bfpair_lo(unsigned v) {
    union { float f; unsigned u; } x; x.u = v << 16; return x.f;
}
static __device__ __forceinline__ float bfpair_hi(unsigned v) {
    union { float f; unsigned u; } x; x.u = v & 0xffff0000u; return x.f;
}
// split f into hi+lo bf16 pair (covers ~16 mantissa bits)
static __device__ __forceinline__ void splitbf(float f, short& hi, short& lo) {
    hi = f2bf(f);
    lo = f2bf(f - bf2f((unsigned short)hi));
}

// ================= CSR build: LDS-bucketed partition (no global data atomics) =================

// R19: fused hist + weight-prep (independent roles by blockIdx -> run concurrently)
__global__ __launch_bounds__(512) void k_hist_prep(const int* __restrict__ dst, int E, int CHUNK,
                                                   int NBLK, int NBUK,
                                                   int* __restrict__ blockhist,
                                                   const float* __restrict__ W1,
                                                   short* __restrict__ w1t,
                                                   const float* __restrict__ W2,
                                                   short* __restrict__ w2ht,
                                                   short* __restrict__ w2lt) {
    __shared__ int hist[MAXBUK];
    int t = threadIdx.x, b = blockIdx.x;
    if (b < NBLK) {
        for (int i = t; i < NBUK; i += 512) hist[i] = 0;
        __syncthreads();
        int e0 = b * CHUNK, e1 = e0 + CHUNK; if (e1 > E) e1 = E;
        for (int e = e0 + t; e < e1; e += 512) atomicAdd(&hist[dst[e] >> BSHIFT], 1);
        __syncthreads();
        for (int i = t; i < NBUK; i += 512) blockhist[(size_t)i * NBLK + b] = hist[i];
    } else {
        int i = (b - NBLK) * 512 + t;    // 22 blocks x 512 = 11264 = 8192 + 3072
        if (i < 64 * 128) {              // W1 -> bf16 transposed [64 n][128 k]
            int n = i >> 7, k = i & 127;
            w1t[i] = f2bf(W1[k * 64 + n]);
        } else if (i < 64 * 128 + 48 * 64) {   // W2 -> hi/lo bf16 transposed [48 n][64 k]
            int j = i - 64 * 128;
            int n = j >> 6, k = j & 63;
            short hi = 0, lo = 0;
            if (n < 40) splitbf(W2[k * 40 + n], hi, lo);
            w2ht[j] = hi; w2lt[j] = lo;
        }
    }
}

// Per-bucket LOCAL exclusive scan across NBLK block-counts (carry loop), writes bucket total.
__global__ __launch_bounds__(256) void k_colscan(int* __restrict__ blockhist,
                                                 int* __restrict__ btot, int NBLK) {
    int bucket = blockIdx.x, t = threadIdx.x;
    int lane = t & 63, wv = t >> 6;
    __shared__ int wsum[4];
    __shared__ int carry_s;
    if (t == 0) carry_s = 0;
    __syncthreads();
    for (int base = 0; base < NBLK; base += 256) {
        int idx = base + t;
        int v = (idx < NBLK) ? blockhist[(size_t)bucket * NBLK + idx] : 0;
        int s = v;
#pragma unroll
        for (int o = 1; o < 64; o <<= 1) {
            int u = __shfl_up(s, o, 64);
            if (lane >= o) s += u;
        }
        if (lane == 63) wsum[wv] = s;
        __syncthreads();
        int b0 = 0;
#pragma unroll
        for (int w = 0; w < 4; ++w) b0 += (w < wv) ? wsum[w] : 0;
        int excl = s + b0 - v + carry_s;
        if (idx < NBLK) blockhist[(size_t)bucket * NBLK + idx] = excl;
        __syncthreads();
        if (t == 255) carry_s += s + b0;   // chunk total
        __syncthreads();
    }
    if (t == 0) btot[bucket] = carry_s;
}

// Exclusive scan over NBUK bucket totals (NBUK <= 512).
__global__ __launch_bounds__(512) void k_bucket_scan(const int* __restrict__ btot,
                                                     int* __restrict__ bucketbase, int NBUK) {
    __shared__ int sh[512];
    int t = threadIdx.x;
    int v = (t < NBUK) ? btot[t] : 0;
    sh[t] = v;
    __syncthreads();
#pragma unroll
    for (int o = 1; o < 512; o <<= 1) {
        int u = (t >= o) ? sh[t - o] : 0;
        __syncthreads();
        sh[t] += u;
        __syncthreads();
    }
    if (t < NBUK) bucketbase[t] = sh[t] - v;
    if (t == NBUK - 1) bucketbase[NBUK] = sh[t];
}

// R19: fused partition + gemm1 (independent roles by blockIdx -> run concurrently).
// Blocks [0,NBLK): partition (packed record: (src<<8)|(dst&255)).
// Blocks [NBLK, NBLK+GB1): layer-1 MFMA GEMM at 512 thr (8 waves, 128 rows/block).
__global__ __launch_bounds__(512) void k_part_gemm1(const int* __restrict__ src,
                                                    const int* __restrict__ dst, int E, int CHUNK,
                                                    int NBLK, int NBUK,
                                                    const int* __restrict__ blockhist,
                                                    const int* __restrict__ bucketbase,
                                                    unsigned* __restrict__ packed,
                                                    const float* __restrict__ x,
                                                    const short* __restrict__ w1t,
                                                    const float* __restrict__ att_s,
                                                    const float* __restrict__ att_d,
                                                    unsigned short* __restrict__ h1b,
                                                    float* __restrict__ a_s1,
                                                    float* __restrict__ a_d1, int N) {
    __shared__ int cur[MAXBUK];
    int t = threadIdx.x, b = blockIdx.x;
    if (b < NBLK) {
        for (int i = t; i < NBUK; i += 512)
            cur[i] = blockhist[(size_t)i * NBLK + b] + bucketbase[i];
        __syncthreads();
        int e0 = b * CHUNK, e1 = e0 + CHUNK; if (e1 > E) e1 = E;
        for (int e = e0 + t; e < e1; e += 512) {
            int d = dst[e], s = src[e];
            int pos = atomicAdd(&cur[d >> BSHIFT], 1);
            packed[pos] = ((unsigned)s << 8) | ((unsigned)d & 255u);
        }
        return;
    }
    // ---- gemm1 role ----
    int wave = t >> 6, lane = t & 63;
    int n16 = lane & 15, q = lane >> 4;
    int nb = (b - NBLK) * 128 + wave * 16;
    if (nb >= N) return;

    short8 bfr[4][4];
#pragma unroll
    for (int ct = 0; ct < 4; ++ct) {
        int n = ct * 16 + n16;
#pragma unroll
        for (int kc = 0; kc < 4; ++kc)
            bfr[ct][kc] = *(const short8*)(w1t + n * 128 + kc * 32 + q * 8);
    }

    int arow = nb + n16; if (arow >= N) arow = N - 1;
    const float* xr = x + (size_t)arow * 128 + q * 8;
    short8 afr[4];
#pragma unroll
    for (int kc = 0; kc < 4; ++kc) {
        float4 u0 = *(const float4*)(xr + kc * 32);
        float4 u1 = *(const float4*)(xr + kc * 32 + 4);
        short8 a;
        a[0] = f2bf(u0.x); a[1] = f2bf(u0.y); a[2] = f2bf(u0.z); a[3] = f2bf(u0.w);
        a[4] = f2bf(u1.x); a[5] = f2bf(u1.y); a[6] = f2bf(u1.z); a[7] = f2bf(u1.w);
        afr[kc] = a;
    }

    floatx4 acc[4];
#pragma unroll
    for (int ct = 0; ct < 4; ++ct) {
        floatx4 c = {0.f, 0.f, 0.f, 0.f};
#pragma unroll
        for (int kc = 0; kc < 4; ++kc)
            c = __builtin_amdgcn_mfma_f32_16x16x32_bf16(afr[kc], bfr[ct][kc], c, 0, 0, 0);
        acc[ct] = c;
    }

#pragma unroll
    for (int ct = 0; ct < 4; ++ct) {
#pragma unroll
        for (int r = 0; r < 4; ++r) {
            int row = nb + q * 4 + r;
            if (row < N) h1b[(size_t)row * 64 + ct * 16 + n16] = (unsigned short)f2bf(acc[ct][r]);
        }
    }

#pragma unroll
    for (int ct = 0; ct < 4; ++ct) {
        float as = att_s[ct * 16 + n16];
        float ad = att_d[ct * 16 + n16];
#pragma unroll
        for (int r = 0; r < 4; ++r) {
            float ps = acc[ct][r] * as;
            float pd = acc[ct][r] * ad;
#pragma unroll
            for (int m = 1; m < 8; m <<= 1) {
                ps += __shfl_xor(ps, m, 64);
                pd += __shfl_xor(pd, m, 64);
            }
            int row = nb + q * 4 + r;
            if ((n16 & 7) == 0 && row < N) {
                int h = 2 * ct + (n16 >> 3);
                a_s1[row * 8 + h] = ps;
                a_d1[row * 8 + h] = pd;
            }
        }
    }
}

__global__ __launch_bounds__(256) void k_fine(const unsigned* __restrict__ packed,
                                              const int* __restrict__ bucketbase,
                                              int* __restrict__ offsets,
                                              int* __restrict__ csr_src,
                                              int N, int NBUK) {
    __shared__ int fcnt[256];
    __shared__ int wsum[4];
    int bucket = blockIdx.x, t = threadIdx.x;
    int lo = bucket << BSHIFT;
    int nn = N - lo; if (nn > 256) nn = 256;
    int ebase = bucketbase[bucket];
    int ecnt = bucketbase[bucket + 1] - ebase;
    fcnt[t] = 0;
    __syncthreads();
    for (int i = t; i < ecnt; i += 256) {
        unsigned p = packed[ebase + i];
        atomicAdd(&fcnt[p & 255u], 1);
    }
    __syncthreads();
    int v = fcnt[t];
    int lane = t & 63, wv = t >> 6;
    int s = v;
#pragma unroll
    for (int o = 1; o < 64; o <<= 1) {
        int u = __shfl_up(s, o, 64);
        if (lane >= o) s += u;
    }
    if (lane == 63) wsum[wv] = s;
    __syncthreads();
    int base = 0;
#pragma unroll
    for (int w = 0; w < 4; ++w) base += (w < wv) ? wsum[w] : 0;
    int excl = s + base - v;
    if (t < nn) offsets[lo + t] = ebase + excl;
    if (bucket == NBUK - 1 && t == 0) offsets[N] = ebase + ecnt;  // == E
    __syncthreads();
    fcnt[t] = excl;   // reuse as cursor
    __syncthreads();
    for (int i = t; i < ecnt; i += 256) {
        unsigned p = packed[ebase + i];
        int pos = atomicAdd(&fcnt[p & 255u], 1);
        csr_src[ebase + pos] = (int)(p >> 8);
    }
}

// ---------------- Layer 1 aggregation: R16 node-per-quarter + 4-deep gather batching --------
// (proven best: ~49.5 us; L2-miss-traffic bound at ~155 MB/dispatch -> structural floor)
__global__ __launch_bounds__(256) void k_agg1(const unsigned short* __restrict__ h1b,
                                              const float* __restrict__ a_s1,
                                              const float* __restrict__ a_d1,
                                              const int* __restrict__ offsets,
                                              const int* __restrict__ csr_src,
                                              const float* __restrict__ b1,
                                              float* __restrict__ y1, int N) {
    int wave = threadIdx.x >> 6, lane = threadIdx.x & 63;
    int q = lane >> 4;                   // quarter = node slot
    int ll = lane & 15;                  // lane within quarter
    int d = (blockIdx.x * 4 + wave) * 4 + q;
    bool dvalid = (d < N);
    int de = dvalid ? d : N - 1;
    int g = ll >> 3;                     // edge slot 0..1
    int c = ll & 7;                      // chunk == head
    float ad = a_d1[de * 8 + c];
    int i0 = offsets[de];
    int deg = dvalid ? (offsets[de + 1] - i0) : 0;
    int dmax = deg;
    dmax = max(dmax, __shfl_xor(dmax, 16, 64));
    dmax = max(dmax, __shfl_xor(dmax, 32, 64));
    float acc[8] = {0.f, 0.f, 0.f, 0.f, 0.f, 0.f, 0.f, 0.f};
    float wsum_l = 0.f;
    if (g == 0) {                        // self-loop on slot 0
        float w0 = lrelu_exp(a_s1[de * 8 + c] + ad);
        uint4 v = *(const uint4*)(h1b + (size_t)de * 64 + 8 * c);
        acc[0] = w0 * bfpair_lo(v.x); acc[1] = w0 * bfpair_hi(v.x);
        acc[2] = w0 * bfpair_lo(v.y); acc[3] = w0 * bfpair_hi(v.y);
        acc[4] = w0 * bfpair_lo(v.z); acc[5] = w0 * bfpair_hi(v.z);
        acc[6] = w0 * bfpair_lo(v.w); acc[7] = w0 * bfpair_hi(v.w);
        wsum_l = w0;
    }
    for (int j = 0; j < dmax; j += 8) {
        int b0 = i0 + j + 4 * g;
        int idx[4]; bool lv[4];
#pragma unroll
        for (int u = 0; u < 4; ++u) {
            int jj = j + 4 * g + u;
            lv[u] = (jj < deg);
            idx[u] = de;
            if (lv[u]) idx[u] = csr_src[b0 + u];
        }
        float ev[4];
#pragma unroll
        for (int u = 0; u < 4; ++u) ev[u] = a_s1[idx[u] * 8 + c] + ad;
        uint4 vv[4];
#pragma unroll
        for (int u = 0; u < 4; ++u)
            vv[u] = *(const uint4*)(h1b + (size_t)idx[u] * 64 + 8 * c);
#pragma unroll
        for (int u = 0; u < 4; ++u) {
            float w = lv[u] ? lrelu_exp(ev[u]) : 0.f;
            wsum_l += w;
            acc[0] = fmaf(w, bfpair_lo(vv[u].x), acc[0]);
            acc[1] = fmaf(w, bfpair_hi(vv[u].x), acc[1]);
            acc[2] = fmaf(w, bfpair_lo(vv[u].y), acc[2]);
            acc[3] = fmaf(w, bfpair_hi(vv[u].y), acc[3]);
            acc[4] = fmaf(w, bfpair_lo(vv[u].z), acc[4]);
            acc[5] = fmaf(w, bfpair_hi(vv[u].z), acc[5]);
            acc[6] = fmaf(w, bfpair_lo(vv[u].w), acc[6]);
            acc[7] = fmaf(w, bfpair_hi(vv[u].w), acc[7]);
        }
    }
    // fold slot 1 into slot 0 (same c): +8 within quarter; wsum rides along (head==chunk)
#pragma unroll
    for (int k = 0; k < 8; ++k) acc[k] += __shfl(acc[k], lane + 8, 64);
    wsum_l += __shfl(wsum_l, lane + 8, 64);
    if (g == 0 && dvalid) {
        float inv = 1.f / (wsum_l + 1e-16f);
        float4 bA = *(const float4*)(b1 + 8 * c);
        float4 bB = *(const float4*)(b1 + 8 * c + 4);
        float o[8];
        o[0] = acc[0] * inv + bA.x;
        o[1] = acc[1] * inv + bA.y;
        o[2] = acc[2] * inv + bA.z;
        o[3] = acc[3] * inv + bA.w;
        o[4] = acc[4] * inv + bB.x;
        o[5] = acc[5] * inv + bB.y;
        o[6] = acc[6] * inv + bB.z;
        o[7] = acc[7] * inv + bB.w;
#pragma unroll
        for (int k = 0; k < 8; ++k) o[k] = o[k] > 0.f ? o[k] : (__expf(o[k]) - 1.f);
        float4 s0 = make_float4(o[0], o[1], o[2], o[3]);
        float4 s1 = make_float4(o[4], o[5], o[6], o[7]);
        *(float4*)(y1 + (size_t)d * 64 + 8 * c) = s0;       // fp32 (precision-critical)
        *(float4*)(y1 + (size_t)d * 64 + 8 * c + 4) = s1;
    }
}

// ---------------- Layer 2 GEMM, split-bf16; h2b stride padded 40->48 (2-line rows) ----------
__global__ __launch_bounds__(256) void k_gemm2(const float* __restrict__ y1,
                                               const short* __restrict__ w2ht,
                                               const short* __restrict__ w2lt,
                                               const float* __restrict__ att_s,
                                               const float* __restrict__ att_d,
                                               unsigned short* __restrict__ h2b,
                                               float* __restrict__ a2s,
                                               float* __restrict__ a2d, int N) {
    int tid = threadIdx.x, wave = tid >> 6, lane = tid & 63;
    int n16 = lane & 15, q = lane >> 4;
    int nb = blockIdx.x * 64 + wave * 16;
    if (nb >= N) return;

    int arow = nb + n16; if (arow >= N) arow = N - 1;
    const float* yr = y1 + (size_t)arow * 64 + q * 8;
    short8 ah[2], al[2];
#pragma unroll
    for (int kc = 0; kc < 2; ++kc) {
        float4 u0 = *(const float4*)(yr + kc * 32);
        float4 u1 = *(const float4*)(yr + kc * 32 + 4);
        short8 h, l; short hi, lo;
        splitbf(u0.x, hi, lo); h[0] = hi; l[0] = lo;
        splitbf(u0.y, hi, lo); h[1] = hi; l[1] = lo;
        splitbf(u0.z, hi, lo); h[2] = hi; l[2] = lo;
        splitbf(u0.w, hi, lo); h[3] = hi; l[3] = lo;
        splitbf(u1.x, hi, lo); h[4] = hi; l[4] = lo;
        splitbf(u1.y, hi, lo); h[5] = hi; l[5] = lo;
        splitbf(u1.z, hi, lo); h[6] = hi; l[6] = lo;
        splitbf(u1.w, hi, lo); h[7] = hi; l[7] = lo;
        ah[kc] = h; al[kc] = l;
    }

    float psr[4] = {0.f, 0.f, 0.f, 0.f}, pdr[4] = {0.f, 0.f, 0.f, 0.f};
#pragma unroll
    for (int ct = 0; ct < 3; ++ct) {
        int n = ct * 16 + n16;
        short8 bh0 = *(const short8*)(w2ht + n * 64 + q * 8);
        short8 bh1 = *(const short8*)(w2ht + n * 64 + 32 + q * 8);
        short8 bl0 = *(const short8*)(w2lt + n * 64 + q * 8);
        short8 bl1 = *(const short8*)(w2lt + n * 64 + 32 + q * 8);
        floatx4 c = {0.f, 0.f, 0.f, 0.f};
        c = __builtin_amdgcn_mfma_f32_16x16x32_bf16(ah[0], bl0, c, 0, 0, 0);
        c = __builtin_amdgcn_mfma_f32_16x16x32_bf16(al[0], bh0, c, 0, 0, 0);
        c = __builtin_amdgcn_mfma_f32_16x16x32_bf16(ah[0], bh0, c, 0, 0, 0);
        c = __builtin_amdgcn_mfma_f32_16x16x32_bf16(ah[1], bl1, c, 0, 0, 0);
        c = __builtin_amdgcn_mfma_f32_16x16x32_bf16(al[1], bh1, c, 0, 0, 0);
        c = __builtin_amdgcn_mfma_f32_16x16x32_bf16(ah[1], bh1, c, 0, 0, 0);

        int col = ct * 16 + n16;
#pragma unroll
        for (int r = 0; r < 4; ++r) {
            int row = nb + q * 4 + r;
            if (col < 40 && row < N) h2b[(size_t)row * 48 + col] = (unsigned short)f2bf(c[r]);
        }
        float asv = (col < 40) ? att_s[col] : 0.f;
        float adv = (col < 40) ? att_d[col] : 0.f;
#pragma unroll
        for (int r = 0; r < 4; ++r) {
            psr[r] = fmaf(c[r], asv, psr[r]);
            pdr[r] = fmaf(c[r], adv, pdr[r]);
        }
    }
#pragma unroll
    for (int r = 0; r < 4; ++r) {
        float ps = psr[r], pd = pdr[r];
#pragma unroll
        for (int m = 1; m < 16; m <<= 1) {
            ps += __shfl_xor(ps, m, 64);
            pd += __shfl_xor(pd, m, 64);
        }
        int row = nb + q * 4 + r;
        if (n16 == 0 && row < N) { a2s[row] = ps; a2d[row] = pd; }
    }
}

// ---------------- Layer 2 aggregation: R16 node-per-quarter + 4-deep gather batching --------
// h2b stride 48 shorts (96B): every row spans exactly 2 cache lines.
__global__ __launch_bounds__(256) void k_agg2(const unsigned short* __restrict__ h2b,
                                              const float* __restrict__ a2s,
                                              const float* __restrict__ a2d,
                                              const int* __restrict__ offsets,
                                              const int* __restrict__ csr_src,
                                              const float* __restrict__ b2,
                                              float* __restrict__ out, int N) {
    int wave = threadIdx.x >> 6, lane = threadIdx.x & 63;
    int q = lane >> 4;                   // quarter = node slot
    int ll = lane & 15;                  // lane within quarter
    int d = (blockIdx.x * 4 + wave) * 4 + q;
    bool dvalid = (d < N);
    int de = dvalid ? d : N - 1;
    int g = ll / 5;                      // edge slot 0..2 (3 for idle lane 15)
    int c = ll - g * 5;                  // 16B chunk 0..4
    bool lane_ok = (ll < 15);
    float ad = a2d[de];
    float w0 = lrelu_exp(a2s[de] + ad);
    int i0 = offsets[de];
    int deg = offsets[de + 1] - i0;
    if (!dvalid) deg = 0;
    int dmax = deg;
    dmax = max(dmax, __shfl_xor(dmax, 16, 64));
    dmax = max(dmax, __shfl_xor(dmax, 32, 64));
    float acc[8] = {0.f, 0.f, 0.f, 0.f, 0.f, 0.f, 0.f, 0.f};
    float wsum_l = 0.f;
    if (g == 0) {                        // self-loop handled by g==0 lanes (ll 0..4)
        uint4 v = *(const uint4*)(h2b + (size_t)de * 48 + 8 * c);
        acc[0] = w0 * bfpair_lo(v.x); acc[1] = w0 * bfpair_hi(v.x);
        acc[2] = w0 * bfpair_lo(v.y); acc[3] = w0 * bfpair_hi(v.y);
        acc[4] = w0 * bfpair_lo(v.z); acc[5] = w0 * bfpair_hi(v.z);
        acc[6] = w0 * bfpair_lo(v.w); acc[7] = w0 * bfpair_hi(v.w);
    }
    for (int j = 0; j < dmax; j += 12) {
        int b0 = i0 + j + 4 * g;
        int idx[4]; bool lv[4];
#pragma unroll
        for (int u = 0; u < 4; ++u) {
            int jj = j + 4 * g + u;
            lv[u] = lane_ok && (jj < deg);
            idx[u] = de;
            if (lv[u]) idx[u] = csr_src[b0 + u];
        }
        float ev[4];
#pragma unroll
        for (int u = 0; u < 4; ++u) ev[u] = a2s[idx[u]] + ad;
        uint4 vv[4];
#pragma unroll
        for (int u = 0; u < 4; ++u)
            vv[u] = *(const uint4*)(h2b + (size_t)idx[u] * 48 + 8 * c);
#pragma unroll
        for (int u = 0; u < 4; ++u) {
            float w = lv[u] ? lrelu_exp(ev[u]) : 0.f;
            if (c == 0) wsum_l += w;     // one counting lane per (quarter, slot)
            acc[0] = fmaf(w, bfpair_lo(vv[u].x), acc[0]);
            acc[1] = fmaf(w, bfpair_hi(vv[u].x), acc[1]);
            acc[2] = fmaf(w, bfpair_lo(vv[u].y), acc[2]);
            acc[3] = fmaf(w, bfpair_hi(vv[u].y), acc[3]);
            acc[4] = fmaf(w, bfpair_lo(vv[u].z), acc[4]);
            acc[5] = fmaf(w, bfpair_hi(vv[u].z), acc[5]);
            acc[6] = fmaf(w, bfpair_lo(vv[u].w), acc[6]);
            acc[7] = fmaf(w, bfpair_hi(vv[u].w), acc[7]);
        }
    }
    // fold 3 edge slots into g==0 lanes (same c): +5, +10 within quarter
#pragma unroll
    for (int k = 0; k < 8; ++k)
        acc[k] += __shfl(acc[k], lane + 5, 64) + __shfl(acc[k], lane + 10, 64);
    wsum_l += __shfl(wsum_l, lane + 5, 64) + __shfl(wsum_l, lane + 10, 64);
    wsum_l = __shfl(wsum_l, lane & 48, 64);       // broadcast quarter total (from ll==0)
    float wsum = wsum_l + w0;
    bool act5 = (ll < 5) && dvalid;
    float inv = 1.f / (wsum + 1e-16f);
    float4 bA = *(const float4*)(b2 + 8 * c);
    float4 bB = *(const float4*)(b2 + 8 * c + 4);
    float o[8];
    o[0] = acc[0] * inv + bA.x;
    o[1] = acc[1] * inv + bA.y;
    o[2] = acc[2] * inv + bA.z;
    o[3] = acc[3] * inv + bA.w;
    o[4] = acc[4] * inv + bB.x;
    o[5] = acc[5] * inv + bB.y;
    o[6] = acc[6] * inv + bB.z;
    o[7] = acc[7] * inv + bB.w;
    // log_softmax over 40 ch: ll 0..4 hold 8 each; 3-step butterfly inside 8-lane group
    float mxl = -INFINITY;
    if (act5) {
        mxl = fmaxf(fmaxf(fmaxf(o[0], o[1]), fmaxf(o[2], o[3])),
                    fmaxf(fmaxf(o[4], o[5]), fmaxf(o[6], o[7])));
    }
#pragma unroll
    for (int mm = 1; mm < 8; mm <<= 1) mxl = fmaxf(mxl, __shfl_xor(mxl, mm, 64));
    float exl = 0.f;
    if (act5) {
#pragma unroll
        for (int k = 0; k < 8; ++k) exl += __expf(o[k] - mxl);
    }
#pragma unroll
    for (int mm = 1; mm < 8; mm <<= 1) exl += __shfl_xor(exl, mm, 64);
    if (act5) {
        float lse = mxl + __logf(exl);
        float4 s0 = make_float4(o[0] - lse, o[1] - lse, o[2] - lse, o[3] - lse);
        float4 s1 = make_float4(o[4] - lse, o[5] - lse, o[6] - lse, o[7] - lse);
        *(float4*)(out + (size_t)d * 40 + 8 * c) = s0;
        *(float4*)(out + (size_t)d * 40 + 8 * c + 4) = s1;
    }
}

// ---------------- launcher ----------------

extern "C" void kernel_launch(void* const* d_in, const int* in_sizes, int n_in,
                              void* d_out, int out_size, void* d_ws, size_t ws_size,
                              hipStream_t stream) {
    const float* x   = (const float*)d_in[0];
    const int*   ei  = (const int*)d_in[1];
    const float* W1  = (const float*)d_in[2];
    const float* as1 = (const float*)d_in[3];
    const float* ad1 = (const float*)d_in[4];
    const float* b1  = (const float*)d_in[5];
    const float* W2  = (const float*)d_in[6];
    const float* as2 = (const float*)d_in[7];
    const float* ad2 = (const float*)d_in[8];
    const float* b2  = (const float*)d_in[9];
    float* out = (float*)d_out;

    int N = in_sizes[0] / 128;   // 100000
    int E = in_sizes[1] / 2;     // 1600000
    const int* src = ei;
    const int* dst = ei + E;

    int NBUK = (N + 255) >> BSHIFT;          // 391
    int CHUNK = 4096;
    int NBLK = (E + CHUNK - 1) / CHUNK;      // 391

    char* ws = (char*)d_ws;
    size_t off = 0;
    auto alloc = [&](size_t bytes) -> char* {
        char* p = ws + off;
        off += (bytes + 255) & ~(size_t)255;
        return p;
    };
    unsigned short* h1b = (unsigned short*)alloc((size_t)N * 64 * 2);   // bf16
    float* a_s1    = (float*)alloc((size_t)N * 8 * 4);
    float* a_d1    = (float*)alloc((size_t)N * 8 * 4);
    float* y1      = (float*)alloc((size_t)N * 64 * 4);                 // fp32 (precision-critical)
    // h2b (bf16 stride-48, 9.6 MB) and packed (uint, 6.4 MB) are temporally disjoint: share.
    size_t shared_sz = (size_t)N * 48 * 2;
    if ((size_t)E * 4 > shared_sz) shared_sz = (size_t)E * 4;
    char*  region  = alloc(shared_sz);
    unsigned short* h2b = (unsigned short*)region;
    unsigned* packed    = (unsigned*)region;
    float* a2s     = (float*)alloc((size_t)N * 4);
    float* a2d     = (float*)alloc((size_t)N * 4);
    int*   offsets = (int*)alloc((size_t)(N + 1) * 4);
    int*   csr_src = (int*)alloc((size_t)E * 4);
    int*   blockhist  = (int*)alloc((size_t)NBUK * NBLK * 4);
    int*   btot       = (int*)alloc((size_t)NBUK * 4);
    int*   bucketbase = (int*)alloc((size_t)(NBUK + 1) * 4);
    short* w1t     = (short*)alloc((size_t)64 * 128 * 2);
    short* w2ht    = (short*)alloc((size_t)48 * 64 * 2);
    short* w2lt    = (short*)alloc((size_t)48 * 64 * 2);

    int nb1 = (N + 15) / 16;     // agg1: 16 nodes per block (4 waves x 4 quarters)
    int nb2 = (N + 15) / 16;     // agg2: 16 nodes per block (4 waves x 4 quarters)
    int gb2 = (N + 63) / 64;     // gemm2: 256 thr
    int GB1 = (N + 127) / 128;   // gemm1 role in fused launch: 512 thr, 128 rows/block
    int PREPB = 22;              // 22*512 = 11264 = 8192 (w1t) + 3072 (w2 pairs)

    k_hist_prep<<<NBLK + PREPB, 512, 0, stream>>>(dst, E, CHUNK, NBLK, NBUK, blockhist,
                                                  W1, w1t, W2, w2ht, w2lt);
    k_colscan<<<NBUK, 256, 0, stream>>>(blockhist, btot, NBLK);
    k_bucket_scan<<<1, 512, 0, stream>>>(btot, bucketbase, NBUK);
    k_part_gemm1<<<NBLK + GB1, 512, 0, stream>>>(src, dst, E, CHUNK, NBLK, NBUK, blockhist,
                                                 bucketbase, packed,
                                                 x, w1t, as1, ad1, h1b, a_s1, a_d1, N);
    k_fine<<<NBUK, 256, 0, stream>>>(packed, bucketbase, offsets, csr_src, N, NBUK);
    k_agg1<<<nb1, 256, 0, stream>>>(h1b, a_s1, a_d1, offsets, csr_src, b1, y1, N);
    k_gemm2<<<gb2, 256, 0, stream>>>(y1, w2ht, w2lt, as2, ad2, h2b, a2s, a2d, N);
    k_agg2<<<nb2, 256, 0, stream>>>(h2b, a2s, a2d, offsets, csr_src, b2, out, N);
}

// Round 9
// 165.908 us; speedup vs baseline: 1.0848x; 1.0330x over previous
//
#include <hip/hip_runtime.h>
#include <math.h>

#define NEG_SLOPE 0.2f
#define BSHIFT 8            // 256 nodes per bucket
#define MAXBUK 512          // supports N up to 131072

typedef __attribute__((ext_vector_type(8))) short short8;   // 8 bf16 (MFMA A/B frag)
typedef __attribute__((ext_vector_type(4))) float floatx4;  // MFMA C/D frag

static __device__ __forceinline__ float lrelu_exp(float e) {
    e = fmaxf(e, NEG_SLOPE * e);
    return __expf(e);
}

// fp32 -> bf16 (round-to-nearest-even)
static __device__ __forceinline__ short f2bf(float f) {
    union { float f; unsigned u; } v; v.f = f;
    unsigned r = v.u + 0x7FFFu + ((v.u >> 16) & 1u);
    return (short)(r >> 16);
}
// bf16 bits -> fp32 (exact)
static __device__ __forceinline__ float bf2f(unsigned short s) {
    union { float f; unsigned u; } v;
    v.u = ((unsigned)s) << 16;
    return v.f;
}
// packed pair of bf16 -> two fp32 (1 shift / 1 and)
static __device__ __forceinline__ float bfpair_lo(unsigned v) {
    union { float f; unsigned u; } x; x.u = v << 16; return x.f;
}
static __device__ __forceinline__ float bfpair_hi(unsigned v) {
    union { float f; unsigned u; } x; x.u = v & 0xffff0000u; return x.f;
}
// split f into hi+lo bf16 pair (covers ~16 mantissa bits)
static __device__ __forceinline__ void splitbf(float f, short& hi, short& lo) {
    hi = f2bf(f);
    lo = f2bf(f - bf2f((unsigned short)hi));
}

// ================= CSR build: LDS-bucketed partition (no global data atomics) =================

// R20: fused hist + W2-prep + gemm1. hist has NO scattered partial-line writes, so it cannot
// poison L2 write-coalescing; gemm1's streaming x-read overlaps hist's LDS-atomic work.
// gemm1 role self-stages W1 in LDS (no dependency on a prep kernel -> no intra-launch race).
__global__ __launch_bounds__(512) void k_hist_gemm1(const int* __restrict__ dst, int E,
                                                    int CHUNK, int NBLK, int NBUK,
                                                    int* __restrict__ blockhist,
                                                    const float* __restrict__ W2,
                                                    short* __restrict__ w2ht,
                                                    short* __restrict__ w2lt,
                                                    const float* __restrict__ x,
                                                    const float* __restrict__ W1,
                                                    const float* __restrict__ att_s,
                                                    const float* __restrict__ att_d,
                                                    unsigned short* __restrict__ h1b,
                                                    float* __restrict__ a_s1,
                                                    float* __restrict__ a_d1, int N) {
    __shared__ int hist[MAXBUK];
    __shared__ short w1s[64 * 136];      // W1 transposed [n][k], stride 136 (2-way-free banks)
    int t = threadIdx.x, b = blockIdx.x;
    if (b < NBLK) {
        // ---- hist role ----
        for (int i = t; i < NBUK; i += 512) hist[i] = 0;
        __syncthreads();
        int e0 = b * CHUNK, e1 = e0 + CHUNK; if (e1 > E) e1 = E;
        for (int e = e0 + t; e < e1; e += 512) atomicAdd(&hist[dst[e] >> BSHIFT], 1);
        __syncthreads();
        for (int i = t; i < NBUK; i += 512) blockhist[(size_t)i * NBLK + b] = hist[i];
        return;
    }
    if (b < NBLK + 6) {
        // ---- W2 prep role: hi/lo bf16 transposed [48 n][64 k] ----
        int j = (b - NBLK) * 512 + t;    // 6*512 = 3072 = 48*64
        if (j < 48 * 64) {
            int n = j >> 6, k = j & 63;
            short hi = 0, lo = 0;
            if (n < 40) splitbf(W2[k * 40 + n], hi, lo);
            w2ht[j] = hi; w2lt[j] = lo;
        }
        return;
    }
    // ---- gemm1 role (8 waves, 128 rows/block) ----
    int gb = b - NBLK - 6;
    for (int i = t; i < 64 * 128; i += 512) {
        int k = i >> 6, n = i & 63;      // W1 row-major coalesced read
        w1s[n * 136 + k] = f2bf(W1[i]);  // transposed LDS store
    }
    __syncthreads();
    int wave = t >> 6, lane = t & 63;
    int n16 = lane & 15, q = lane >> 4;
    int nb = gb * 128 + wave * 16;
    if (nb >= N) return;

    short8 bfr[4][4];
#pragma unroll
    for (int ct = 0; ct < 4; ++ct) {
        int n = ct * 16 + n16;
#pragma unroll
        for (int kc = 0; kc < 4; ++kc)
            bfr[ct][kc] = *(const short8*)(w1s + n * 136 + kc * 32 + q * 8);
    }

    int arow = nb + n16; if (arow >= N) arow = N - 1;
    const float* xr = x + (size_t)arow * 128 + q * 8;
    short8 afr[4];
#pragma unroll
    for (int kc = 0; kc < 4; ++kc) {
        float4 u0 = *(const float4*)(xr + kc * 32);
        float4 u1 = *(const float4*)(xr + kc * 32 + 4);
        short8 a;
        a[0] = f2bf(u0.x); a[1] = f2bf(u0.y); a[2] = f2bf(u0.z); a[3] = f2bf(u0.w);
        a[4] = f2bf(u1.x); a[5] = f2bf(u1.y); a[6] = f2bf(u1.z); a[7] = f2bf(u1.w);
        afr[kc] = a;
    }

    floatx4 acc[4];
#pragma unroll
    for (int ct = 0; ct < 4; ++ct) {
        floatx4 c = {0.f, 0.f, 0.f, 0.f};
#pragma unroll
        for (int kc = 0; kc < 4; ++kc)
            c = __builtin_amdgcn_mfma_f32_16x16x32_bf16(afr[kc], bfr[ct][kc], c, 0, 0, 0);
        acc[ct] = c;
    }

#pragma unroll
    for (int ct = 0; ct < 4; ++ct) {
#pragma unroll
        for (int r = 0; r < 4; ++r) {
            int row = nb + q * 4 + r;
            if (row < N) h1b[(size_t)row * 64 + ct * 16 + n16] = (unsigned short)f2bf(acc[ct][r]);
        }
    }

#pragma unroll
    for (int ct = 0; ct < 4; ++ct) {
        float as = att_s[ct * 16 + n16];
        float ad = att_d[ct * 16 + n16];
#pragma unroll
        for (int r = 0; r < 4; ++r) {
            float ps = acc[ct][r] * as;
            float pd = acc[ct][r] * ad;
#pragma unroll
            for (int m = 1; m < 8; m <<= 1) {
                ps += __shfl_xor(ps, m, 64);
                pd += __shfl_xor(pd, m, 64);
            }
            int row = nb + q * 4 + r;
            if ((n16 & 7) == 0 && row < N) {
                int h = 2 * ct + (n16 >> 3);
                a_s1[row * 8 + h] = ps;
                a_d1[row * 8 + h] = pd;
            }
        }
    }
}

// Per-bucket LOCAL exclusive scan across NBLK block-counts (carry loop), writes bucket total.
__global__ __launch_bounds__(256) void k_colscan(int* __restrict__ blockhist,
                                                 int* __restrict__ btot, int NBLK) {
    int bucket = blockIdx.x, t = threadIdx.x;
    int lane = t & 63, wv = t >> 6;
    __shared__ int wsum[4];
    __shared__ int carry_s;
    if (t == 0) carry_s = 0;
    __syncthreads();
    for (int base = 0; base < NBLK; base += 256) {
        int idx = base + t;
        int v = (idx < NBLK) ? blockhist[(size_t)bucket * NBLK + idx] : 0;
        int s = v;
#pragma unroll
        for (int o = 1; o < 64; o <<= 1) {
            int u = __shfl_up(s, o, 64);
            if (lane >= o) s += u;
        }
        if (lane == 63) wsum[wv] = s;
        __syncthreads();
        int b0 = 0;
#pragma unroll
        for (int w = 0; w < 4; ++w) b0 += (w < wv) ? wsum[w] : 0;
        int excl = s + b0 - v + carry_s;
        if (idx < NBLK) blockhist[(size_t)bucket * NBLK + idx] = excl;
        __syncthreads();
        if (t == 255) carry_s += s + b0;   // chunk total
        __syncthreads();
    }
    if (t == 0) btot[bucket] = carry_s;
}

// Exclusive scan over NBUK bucket totals (NBUK <= 512).
__global__ __launch_bounds__(512) void k_bucket_scan(const int* __restrict__ btot,
                                                     int* __restrict__ bucketbase, int NBUK) {
    __shared__ int sh[512];
    int t = threadIdx.x;
    int v = (t < NBUK) ? btot[t] : 0;
    sh[t] = v;
    __syncthreads();
#pragma unroll
    for (int o = 1; o < 512; o <<= 1) {
        int u = (t >= o) ? sh[t - o] : 0;
        __syncthreads();
        sh[t] += u;
        __syncthreads();
    }
    if (t < NBUK) bucketbase[t] = sh[t] - v;
    if (t == NBUK - 1) bucketbase[NBUK] = sh[t];
}

// SOLO partition (R20: unfused so its packed[] partial-line writes coalesce in L2).
// packed record: (src << 8) | (dst & 255)   [src < 2^24; bucket id recovers dst high bits]
__global__ __launch_bounds__(512) void k_partition(const int* __restrict__ src,
                                                   const int* __restrict__ dst, int E, int CHUNK,
                                                   int NBLK, int NBUK,
                                                   const int* __restrict__ blockhist,
                                                   const int* __restrict__ bucketbase,
                                                   unsigned* __restrict__ packed) {
    __shared__ int cur[MAXBUK];
    int t = threadIdx.x, b = blockIdx.x;
    for (int i = t; i < NBUK; i += 512)
        cur[i] = blockhist[(size_t)i * NBLK + b] + bucketbase[i];
    __syncthreads();
    int e0 = b * CHUNK, e1 = e0 + CHUNK; if (e1 > E) e1 = E;
    for (int e = e0 + t; e < e1; e += 512) {
        int d = dst[e], s = src[e];
        int pos = atomicAdd(&cur[d >> BSHIFT], 1);
        packed[pos] = ((unsigned)s << 8) | ((unsigned)d & 255u);
    }
}

__global__ __launch_bounds__(256) void k_fine(const unsigned* __restrict__ packed,
                                              const int* __restrict__ bucketbase,
                                              int* __restrict__ offsets,
                                              int* __restrict__ csr_src,
                                              int N, int NBUK) {
    __shared__ int fcnt[256];
    __shared__ int wsum[4];
    int bucket = blockIdx.x, t = threadIdx.x;
    int lo = bucket << BSHIFT;
    int nn = N - lo; if (nn > 256) nn = 256;
    int ebase = bucketbase[bucket];
    int ecnt = bucketbase[bucket + 1] - ebase;
    fcnt[t] = 0;
    __syncthreads();
    for (int i = t; i < ecnt; i += 256) {
        unsigned p = packed[ebase + i];
        atomicAdd(&fcnt[p & 255u], 1);
    }
    __syncthreads();
    int v = fcnt[t];
    int lane = t & 63, wv = t >> 6;
    int s = v;
#pragma unroll
    for (int o = 1; o < 64; o <<= 1) {
        int u = __shfl_up(s, o, 64);
        if (lane >= o) s += u;
    }
    if (lane == 63) wsum[wv] = s;
    __syncthreads();
    int base = 0;
#pragma unroll
    for (int w = 0; w < 4; ++w) base += (w < wv) ? wsum[w] : 0;
    int excl = s + base - v;
    if (t < nn) offsets[lo + t] = ebase + excl;
    if (bucket == NBUK - 1 && t == 0) offsets[N] = ebase + ecnt;  // == E
    __syncthreads();
    fcnt[t] = excl;   // reuse as cursor
    __syncthreads();
    for (int i = t; i < ecnt; i += 256) {
        unsigned p = packed[ebase + i];
        int pos = atomicAdd(&fcnt[p & 255u], 1);
        csr_src[ebase + pos] = (int)(p >> 8);
    }
}

// ---------------- Layer 1 aggregation: R16 node-per-quarter + 4-deep gather batching --------
// (proven best: ~49.5 us; L2-miss-traffic bound at ~155 MB/dispatch -> structural floor)
__global__ __launch_bounds__(256) void k_agg1(const unsigned short* __restrict__ h1b,
                                              const float* __restrict__ a_s1,
                                              const float* __restrict__ a_d1,
                                              const int* __restrict__ offsets,
                                              const int* __restrict__ csr_src,
                                              const float* __restrict__ b1,
                                              float* __restrict__ y1, int N) {
    int wave = threadIdx.x >> 6, lane = threadIdx.x & 63;
    int q = lane >> 4;                   // quarter = node slot
    int ll = lane & 15;                  // lane within quarter
    int d = (blockIdx.x * 4 + wave) * 4 + q;
    bool dvalid = (d < N);
    int de = dvalid ? d : N - 1;
    int g = ll >> 3;                     // edge slot 0..1
    int c = ll & 7;                      // chunk == head
    float ad = a_d1[de * 8 + c];
    int i0 = offsets[de];
    int deg = dvalid ? (offsets[de + 1] - i0) : 0;
    int dmax = deg;
    dmax = max(dmax, __shfl_xor(dmax, 16, 64));
    dmax = max(dmax, __shfl_xor(dmax, 32, 64));
    float acc[8] = {0.f, 0.f, 0.f, 0.f, 0.f, 0.f, 0.f, 0.f};
    float wsum_l = 0.f;
    if (g == 0) {                        // self-loop on slot 0
        float w0 = lrelu_exp(a_s1[de * 8 + c] + ad);
        uint4 v = *(const uint4*)(h1b + (size_t)de * 64 + 8 * c);
        acc[0] = w0 * bfpair_lo(v.x); acc[1] = w0 * bfpair_hi(v.x);
        acc[2] = w0 * bfpair_lo(v.y); acc[3] = w0 * bfpair_hi(v.y);
        acc[4] = w0 * bfpair_lo(v.z); acc[5] = w0 * bfpair_hi(v.z);
        acc[6] = w0 * bfpair_lo(v.w); acc[7] = w0 * bfpair_hi(v.w);
        wsum_l = w0;
    }
    for (int j = 0; j < dmax; j += 8) {
        int b0 = i0 + j + 4 * g;
        int idx[4]; bool lv[4];
#pragma unroll
        for (int u = 0; u < 4; ++u) {
            int jj = j + 4 * g + u;
            lv[u] = (jj < deg);
            idx[u] = de;
            if (lv[u]) idx[u] = csr_src[b0 + u];
        }
        float ev[4];
#pragma unroll
        for (int u = 0; u < 4; ++u) ev[u] = a_s1[idx[u] * 8 + c] + ad;
        uint4 vv[4];
#pragma unroll
        for (int u = 0; u < 4; ++u)
            vv[u] = *(const uint4*)(h1b + (size_t)idx[u] * 64 + 8 * c);
#pragma unroll
        for (int u = 0; u < 4; ++u) {
            float w = lv[u] ? lrelu_exp(ev[u]) : 0.f;
            wsum_l += w;
            acc[0] = fmaf(w, bfpair_lo(vv[u].x), acc[0]);
            acc[1] = fmaf(w, bfpair_hi(vv[u].x), acc[1]);
            acc[2] = fmaf(w, bfpair_lo(vv[u].y), acc[2]);
            acc[3] = fmaf(w, bfpair_hi(vv[u].y), acc[3]);
            acc[4] = fmaf(w, bfpair_lo(vv[u].z), acc[4]);
            acc[5] = fmaf(w, bfpair_hi(vv[u].z), acc[5]);
            acc[6] = fmaf(w, bfpair_lo(vv[u].w), acc[6]);
            acc[7] = fmaf(w, bfpair_hi(vv[u].w), acc[7]);
        }
    }
    // fold slot 1 into slot 0 (same c): +8 within quarter; wsum rides along (head==chunk)
#pragma unroll
    for (int k = 0; k < 8; ++k) acc[k] += __shfl(acc[k], lane + 8, 64);
    wsum_l += __shfl(wsum_l, lane + 8, 64);
    if (g == 0 && dvalid) {
        float inv = 1.f / (wsum_l + 1e-16f);
        float4 bA = *(const float4*)(b1 + 8 * c);
        float4 bB = *(const float4*)(b1 + 8 * c + 4);
        float o[8];
        o[0] = acc[0] * inv + bA.x;
        o[1] = acc[1] * inv + bA.y;
        o[2] = acc[2] * inv + bA.z;
        o[3] = acc[3] * inv + bA.w;
        o[4] = acc[4] * inv + bB.x;
        o[5] = acc[5] * inv + bB.y;
        o[6] = acc[6] * inv + bB.z;
        o[7] = acc[7] * inv + bB.w;
#pragma unroll
        for (int k = 0; k < 8; ++k) o[k] = o[k] > 0.f ? o[k] : (__expf(o[k]) - 1.f);
        float4 s0 = make_float4(o[0], o[1], o[2], o[3]);
        float4 s1 = make_float4(o[4], o[5], o[6], o[7]);
        *(float4*)(y1 + (size_t)d * 64 + 8 * c) = s0;       // fp32 (precision-critical)
        *(float4*)(y1 + (size_t)d * 64 + 8 * c + 4) = s1;
    }
}

// ---------------- Layer 2 GEMM, split-bf16; h2b stride padded 40->48 (2-line rows) ----------
__global__ __launch_bounds__(256) void k_gemm2(const float* __restrict__ y1,
                                               const short* __restrict__ w2ht,
                                               const short* __restrict__ w2lt,
                                               const float* __restrict__ att_s,
                                               const float* __restrict__ att_d,
                                               unsigned short* __restrict__ h2b,
                                               float* __restrict__ a2s,
                                               float* __restrict__ a2d, int N) {
    int tid = threadIdx.x, wave = tid >> 6, lane = tid & 63;
    int n16 = lane & 15, q = lane >> 4;
    int nb = blockIdx.x * 64 + wave * 16;
    if (nb >= N) return;

    int arow = nb + n16; if (arow >= N) arow = N - 1;
    const float* yr = y1 + (size_t)arow * 64 + q * 8;
    short8 ah[2], al[2];
#pragma unroll
    for (int kc = 0; kc < 2; ++kc) {
        float4 u0 = *(const float4*)(yr + kc * 32);
        float4 u1 = *(const float4*)(yr + kc * 32 + 4);
        short8 h, l; short hi, lo;
        splitbf(u0.x, hi, lo); h[0] = hi; l[0] = lo;
        splitbf(u0.y, hi, lo); h[1] = hi; l[1] = lo;
        splitbf(u0.z, hi, lo); h[2] = hi; l[2] = lo;
        splitbf(u0.w, hi, lo); h[3] = hi; l[3] = lo;
        splitbf(u1.x, hi, lo); h[4] = hi; l[4] = lo;
        splitbf(u1.y, hi, lo); h[5] = hi; l[5] = lo;
        splitbf(u1.z, hi, lo); h[6] = hi; l[6] = lo;
        splitbf(u1.w, hi, lo); h[7] = hi; l[7] = lo;
        ah[kc] = h; al[kc] = l;
    }

    float psr[4] = {0.f, 0.f, 0.f, 0.f}, pdr[4] = {0.f, 0.f, 0.f, 0.f};
#pragma unroll
    for (int ct = 0; ct < 3; ++ct) {
        int n = ct * 16 + n16;
        short8 bh0 = *(const short8*)(w2ht + n * 64 + q * 8);
        short8 bh1 = *(const short8*)(w2ht + n * 64 + 32 + q * 8);
        short8 bl0 = *(const short8*)(w2lt + n * 64 + q * 8);
        short8 bl1 = *(const short8*)(w2lt + n * 64 + 32 + q * 8);
        floatx4 c = {0.f, 0.f, 0.f, 0.f};
        c = __builtin_amdgcn_mfma_f32_16x16x32_bf16(ah[0], bl0, c, 0, 0, 0);
        c = __builtin_amdgcn_mfma_f32_16x16x32_bf16(al[0], bh0, c, 0, 0, 0);
        c = __builtin_amdgcn_mfma_f32_16x16x32_bf16(ah[0], bh0, c, 0, 0, 0);
        c = __builtin_amdgcn_mfma_f32_16x16x32_bf16(ah[1], bl1, c, 0, 0, 0);
        c = __builtin_amdgcn_mfma_f32_16x16x32_bf16(al[1], bh1, c, 0, 0, 0);
        c = __builtin_amdgcn_mfma_f32_16x16x32_bf16(ah[1], bh1, c, 0, 0, 0);

        int col = ct * 16 + n16;
#pragma unroll
        for (int r = 0; r < 4; ++r) {
            int row = nb + q * 4 + r;
            if (col < 40 && row < N) h2b[(size_t)row * 48 + col] = (unsigned short)f2bf(c[r]);
        }
        float asv = (col < 40) ? att_s[col] : 0.f;
        float adv = (col < 40) ? att_d[col] : 0.f;
#pragma unroll
        for (int r = 0; r < 4; ++r) {
            psr[r] = fmaf(c[r], asv, psr[r]);
            pdr[r] = fmaf(c[r], adv, pdr[r]);
        }
    }
#pragma unroll
    for (int r = 0; r < 4; ++r) {
        float ps = psr[r], pd = pdr[r];
#pragma unroll
        for (int m = 1; m < 16; m <<= 1) {
            ps += __shfl_xor(ps, m, 64);
            pd += __shfl_xor(pd, m, 64);
        }
        int row = nb + q * 4 + r;
        if (n16 == 0 && row < N) { a2s[row] = ps; a2d[row] = pd; }
    }
}

// ---------------- Layer 2 aggregation: R16 node-per-quarter + 4-deep gather batching --------
// h2b stride 48 shorts (96B): every row spans exactly 2 cache lines.
__global__ __launch_bounds__(256) void k_agg2(const unsigned short* __restrict__ h2b,
                                              const float* __restrict__ a2s,
                                              const float* __restrict__ a2d,
                                              const int* __restrict__ offsets,
                                              const int* __restrict__ csr_src,
                                              const float* __restrict__ b2,
                                              float* __restrict__ out, int N) {
    int wave = threadIdx.x >> 6, lane = threadIdx.x & 63;
    int q = lane >> 4;                   // quarter = node slot
    int ll = lane & 15;                  // lane within quarter
    int d = (blockIdx.x * 4 + wave) * 4 + q;
    bool dvalid = (d < N);
    int de = dvalid ? d : N - 1;
    int g = ll / 5;                      // edge slot 0..2 (3 for idle lane 15)
    int c = ll - g * 5;                  // 16B chunk 0..4
    bool lane_ok = (ll < 15);
    float ad = a2d[de];
    float w0 = lrelu_exp(a2s[de] + ad);
    int i0 = offsets[de];
    int deg = offsets[de + 1] - i0;
    if (!dvalid) deg = 0;
    int dmax = deg;
    dmax = max(dmax, __shfl_xor(dmax, 16, 64));
    dmax = max(dmax, __shfl_xor(dmax, 32, 64));
    float acc[8] = {0.f, 0.f, 0.f, 0.f, 0.f, 0.f, 0.f, 0.f};
    float wsum_l = 0.f;
    if (g == 0) {                        // self-loop handled by g==0 lanes (ll 0..4)
        uint4 v = *(const uint4*)(h2b + (size_t)de * 48 + 8 * c);
        acc[0] = w0 * bfpair_lo(v.x); acc[1] = w0 * bfpair_hi(v.x);
        acc[2] = w0 * bfpair_lo(v.y); acc[3] = w0 * bfpair_hi(v.y);
        acc[4] = w0 * bfpair_lo(v.z); acc[5] = w0 * bfpair_hi(v.z);
        acc[6] = w0 * bfpair_lo(v.w); acc[7] = w0 * bfpair_hi(v.w);
    }
    for (int j = 0; j < dmax; j += 12) {
        int b0 = i0 + j + 4 * g;
        int idx[4]; bool lv[4];
#pragma unroll
        for (int u = 0; u < 4; ++u) {
            int jj = j + 4 * g + u;
            lv[u] = lane_ok && (jj < deg);
            idx[u] = de;
            if (lv[u]) idx[u] = csr_src[b0 + u];
        }
        float ev[4];
#pragma unroll
        for (int u = 0; u < 4; ++u) ev[u] = a2s[idx[u]] + ad;
        uint4 vv[4];
#pragma unroll
        for (int u = 0; u < 4; ++u)
            vv[u] = *(const uint4*)(h2b + (size_t)idx[u] * 48 + 8 * c);
#pragma unroll
        for (int u = 0; u < 4; ++u) {
            float w = lv[u] ? lrelu_exp(ev[u]) : 0.f;
            if (c == 0) wsum_l += w;     // one counting lane per (quarter, slot)
            acc[0] = fmaf(w, bfpair_lo(vv[u].x), acc[0]);
            acc[1] = fmaf(w, bfpair_hi(vv[u].x), acc[1]);
            acc[2] = fmaf(w, bfpair_lo(vv[u].y), acc[2]);
            acc[3] = fmaf(w, bfpair_hi(vv[u].y), acc[3]);
            acc[4] = fmaf(w, bfpair_lo(vv[u].z), acc[4]);
            acc[5] = fmaf(w, bfpair_hi(vv[u].z), acc[5]);
            acc[6] = fmaf(w, bfpair_lo(vv[u].w), acc[6]);
            acc[7] = fmaf(w, bfpair_hi(vv[u].w), acc[7]);
        }
    }
    // fold 3 edge slots into g==0 lanes (same c): +5, +10 within quarter
#pragma unroll
    for (int k = 0; k < 8; ++k)
        acc[k] += __shfl(acc[k], lane + 5, 64) + __shfl(acc[k], lane + 10, 64);
    wsum_l += __shfl(wsum_l, lane + 5, 64) + __shfl(wsum_l, lane + 10, 64);
    wsum_l = __shfl(wsum_l, lane & 48, 64);       // broadcast quarter total (from ll==0)
    float wsum = wsum_l + w0;
    bool act5 = (ll < 5) && dvalid;
    float inv = 1.f / (wsum + 1e-16f);
    float4 bA = *(const float4*)(b2 + 8 * c);
    float4 bB = *(const float4*)(b2 + 8 * c + 4);
    float o[8];
    o[0] = acc[0] * inv + bA.x;
    o[1] = acc[1] * inv + bA.y;
    o[2] = acc[2] * inv + bA.z;
    o[3] = acc[3] * inv + bA.w;
    o[4] = acc[4] * inv + bB.x;
    o[5] = acc[5] * inv + bB.y;
    o[6] = acc[6] * inv + bB.z;
    o[7] = acc[7] * inv + bB.w;
    // log_softmax over 40 ch: ll 0..4 hold 8 each; 3-step butterfly inside 8-lane group
    float mxl = -INFINITY;
    if (act5) {
        mxl = fmaxf(fmaxf(fmaxf(o[0], o[1]), fmaxf(o[2], o[3])),
                    fmaxf(fmaxf(o[4], o[5]), fmaxf(o[6], o[7])));
    }
#pragma unroll
    for (int mm = 1; mm < 8; mm <<= 1) mxl = fmaxf(mxl, __shfl_xor(mxl, mm, 64));
    float exl = 0.f;
    if (act5) {
#pragma unroll
        for (int k = 0; k < 8; ++k) exl += __expf(o[k] - mxl);
    }
#pragma unroll
    for (int mm = 1; mm < 8; mm <<= 1) exl += __shfl_xor(exl, mm, 64);
    if (act5) {
        float lse = mxl + __logf(exl);
        float4 s0 = make_float4(o[0] - lse, o[1] - lse, o[2] - lse, o[3] - lse);
        float4 s1 = make_float4(o[4] - lse, o[5] - lse, o[6] - lse, o[7] - lse);
        *(float4*)(out + (size_t)d * 40 + 8 * c) = s0;
        *(float4*)(out + (size_t)d * 40 + 8 * c + 4) = s1;
    }
}

// ---------------- launcher ----------------

extern "C" void kernel_launch(void* const* d_in, const int* in_sizes, int n_in,
                              void* d_out, int out_size, void* d_ws, size_t ws_size,
                              hipStream_t stream) {
    const float* x   = (const float*)d_in[0];
    const int*   ei  = (const int*)d_in[1];
    const float* W1  = (const float*)d_in[2];
    const float* as1 = (const float*)d_in[3];
    const float* ad1 = (const float*)d_in[4];
    const float* b1  = (const float*)d_in[5];
    const float* W2  = (const float*)d_in[6];
    const float* as2 = (const float*)d_in[7];
    const float* ad2 = (const float*)d_in[8];
    const float* b2  = (const float*)d_in[9];
    float* out = (float*)d_out;

    int N = in_sizes[0] / 128;   // 100000
    int E = in_sizes[1] / 2;     // 1600000
    const int* src = ei;
    const int* dst = ei + E;

    int NBUK = (N + 255) >> BSHIFT;          // 391
    int CHUNK = 4096;
    int NBLK = (E + CHUNK - 1) / CHUNK;      // 391

    char* ws = (char*)d_ws;
    size_t off = 0;
    auto alloc = [&](size_t bytes) -> char* {
        char* p = ws + off;
        off += (bytes + 255) & ~(size_t)255;
        return p;
    };
    unsigned short* h1b = (unsigned short*)alloc((size_t)N * 64 * 2);   // bf16
    float* a_s1    = (float*)alloc((size_t)N * 8 * 4);
    float* a_d1    = (float*)alloc((size_t)N * 8 * 4);
    float* y1      = (float*)alloc((size_t)N * 64 * 4);                 // fp32 (precision-critical)
    // h2b (bf16 stride-48, 9.6 MB) and packed (uint, 6.4 MB) are temporally disjoint: share.
    size_t shared_sz = (size_t)N * 48 * 2;
    if ((size_t)E * 4 > shared_sz) shared_sz = (size_t)E * 4;
    char*  region  = alloc(shared_sz);
    unsigned short* h2b = (unsigned short*)region;
    unsigned* packed    = (unsigned*)region;
    float* a2s     = (float*)alloc((size_t)N * 4);
    float* a2d     = (float*)alloc((size_t)N * 4);
    int*   offsets = (int*)alloc((size_t)(N + 1) * 4);
    int*   csr_src = (int*)alloc((size_t)E * 4);
    int*   blockhist  = (int*)alloc((size_t)NBUK * NBLK * 4);
    int*   btot       = (int*)alloc((size_t)NBUK * 4);
    int*   bucketbase = (int*)alloc((size_t)(NBUK + 1) * 4);
    short* w2ht    = (short*)alloc((size_t)48 * 64 * 2);
    short* w2lt    = (short*)alloc((size_t)48 * 64 * 2);

    int nb1 = (N + 15) / 16;     // agg1: 16 nodes per block (4 waves x 4 quarters)
    int nb2 = (N + 15) / 16;     // agg2: 16 nodes per block (4 waves x 4 quarters)
    int gb2 = (N + 63) / 64;     // gemm2: 256 thr
    int GB1 = (N + 127) / 128;   // gemm1 role: 512 thr, 128 rows/block
    int W2B = 6;                 // 6*512 = 3072 = 48*64 W2 elements

    k_hist_gemm1<<<NBLK + W2B + GB1, 512, 0, stream>>>(dst, E, CHUNK, NBLK, NBUK, blockhist,
                                                       W2, w2ht, w2lt,
                                                       x, W1, as1, ad1, h1b, a_s1, a_d1, N);
    k_colscan<<<NBUK, 256, 0, stream>>>(blockhist, btot, NBLK);
    k_bucket_scan<<<1, 512, 0, stream>>>(btot, bucketbase, NBUK);
    k_partition<<<NBLK, 512, 0, stream>>>(src, dst, E, CHUNK, NBLK, NBUK, blockhist,
                                          bucketbase, packed);
    k_fine<<<NBUK, 256, 0, stream>>>(packed, bucketbase, offsets, csr_src, N, NBUK);
    k_agg1<<<nb1, 256, 0, stream>>>(h1b, a_s1, a_d1, offsets, csr_src, b1, y1, N);
    k_gemm2<<<gb2, 256, 0, stream>>>(y1, w2ht, w2lt, as2, ad2, h2b, a2s, a2d, N);
    k_agg2<<<nb2, 256, 0, stream>>>(h2b, a2s, a2d, offsets, csr_src, b2, out, N);
}